// Round 6
// baseline (401.490 us; speedup 1.0000x reference)
//
#include <hip/hip_runtime.h>
#include <hip/hip_bf16.h>
#include <hip/hip_cooperative_groups.h>

namespace cg = cooperative_groups;

// FEELModel, cooperative mega-kernel with runtime-sized grid + checked fallback
// to the proven 8-kernel chain.
// phases: 1 emb fp32->fp8 | 2 gather + weight-prep | 3 leaf-IOU GEMM + dots
//         4 leaf act | 5 root GEMMs | 6 root act | 7 sim GEMM | 8 final
// B=512, L=64, Lq=128, D=M=512, 3M=1536, H=256, O=30

typedef __attribute__((ext_vector_type(8))) short short8;   // 8 bf16
typedef __attribute__((ext_vector_type(4))) float floatx4;  // MFMA C/D frag
typedef __attribute__((ext_vector_type(2))) float floatx2;

__device__ inline ushort f2bf(float f) {            // fp32 -> bf16 bits, RNE
    unsigned u = __float_as_uint(f);
    u += 0x7fffu + ((u >> 16) & 1u);
    return (ushort)(u >> 16);
}
__device__ inline float bf2f(ushort u) { return __uint_as_float((unsigned)u << 16); }
__device__ inline float sigm(float x) { return 1.0f / (1.0f + expf(-x)); }

#if defined(__has_builtin)
#if __has_builtin(__builtin_amdgcn_cvt_pk_f32_fp8) && __has_builtin(__builtin_amdgcn_cvt_pk_fp8_f32)
#define HW_FP8 1
#endif
#endif

#ifndef HW_FP8
__device__ inline unsigned enc1(float x) {          // manual e4m3fn encode, RNE, saturating
    float a = fabsf(x);
    unsigned s = (__float_as_uint(x) >> 31) << 7;
    unsigned b = __float_as_uint(a);
    unsigned uexp = b >> 23;
    if (uexp < 121) {
        int m = (int)(a * 512.0f + 0.5f);
        if (m >= 8) return s | 0x08u;
        return s | (unsigned)m;
    }
    b += 0x00080000u;
    unsigned e = b >> 23;
    if (e > 135u) return s | 0x7Eu;
    return s | ((e - 120u) << 3) | ((b >> 20) & 7u);
}
__device__ inline float dec1(unsigned v) {
    unsigned s = (v >> 7) & 1u, e = (v >> 3) & 15u, m = v & 7u;
    float r = e ? __uint_as_float(((e + 120u) << 23) | (m << 20))
                : (float)m * 0.001953125f;
    return s ? -r : r;
}
#endif

__device__ inline unsigned pk4(float a, float b, float c, float d) {
#ifdef HW_FP8
    int v = 0;
    v = __builtin_amdgcn_cvt_pk_fp8_f32(a, b, v, false);
    v = __builtin_amdgcn_cvt_pk_fp8_f32(c, d, v, true);
    return (unsigned)v;
#else
    return enc1(a) | (enc1(b) << 8) | (enc1(c) << 16) | (enc1(d) << 24);
#endif
}
__device__ inline void dec4_add(unsigned v, float* acc) {
#ifdef HW_FP8
    floatx2 p0 = __builtin_amdgcn_cvt_pk_f32_fp8(v, false);
    floatx2 p1 = __builtin_amdgcn_cvt_pk_f32_fp8(v, true);
    acc[0] += p0[0]; acc[1] += p0[1]; acc[2] += p1[0]; acc[3] += p1[1];
#else
    acc[0] += dec1(v & 255u); acc[1] += dec1((v >> 8) & 255u);
    acc[2] += dec1((v >> 16) & 255u); acc[3] += dec1(v >> 24);
#endif
}

#define GLD16(gp, sp)                                                        \
    __builtin_amdgcn_global_load_lds(                                        \
        (const __attribute__((address_space(1))) unsigned int*)(const void*)(gp), \
        (__attribute__((address_space(3))) unsigned int*)(void*)(sp), 16, 0, 0)

#define FP8_SCALE 64.0f

// unit counts
#define N_CONV   12500
#define N_GATHER 9728
#define N_WPREP  2177
#define N_PH2    (N_GATHER + N_WPREP)   // 11905
#define N_PH3    944
#define N_LEAF   1536
#define N_GEMM3  336
#define N_ROOT   1536
#define N_SIM    16
#define N_FINAL  512

struct Params {
    const int *q_v, *qa0, *na0, *qa1, *na1, *qa2, *na2, *query, *pos, *neg;
    const float *emb, *Wioux, *bioux, *Wiouh, *biouh, *Wfx, *bfx, *Wfh, *bfh,
                *Wwh, *bwh, *Wwp, *bwp;
    float* out;
    ushort *Wcat_t, *Wfh_t, *Wfx_t, *Wwh_t;
    float *wsum, *lossv;
    ushort *Xleaf, *XR;
    unsigned char* emb8;
    float* pools;
    ushort *IOU_l, *c_l, *h_l, *FH, *FX, *IOU_r;
    float *c_root, *S;
    int nblk;
};

// ---------------- phase units ----------------

__device__ __forceinline__ void conv_unit(int blk, int tid, const Params& p) {
    size_t i = ((size_t)blk * 256 + tid) * 8;
    float4 a = *(const float4*)(p.emb + i);
    float4 b = *(const float4*)(p.emb + i + 4);
    uint2 o;
    o.x = pk4(a.x * FP8_SCALE, a.y * FP8_SCALE, a.z * FP8_SCALE, a.w * FP8_SCALE);
    o.y = pk4(b.x * FP8_SCALE, b.y * FP8_SCALE, b.z * FP8_SCALE, b.w * FP8_SCALE);
    *(uint2*)(p.emb8 + i) = o;
}

// blk in [0, 2177): 0..1535 Wcat, 1536..1791 Wfh, 1792..2047 Wfx, 2048..2175 Wwh, 2176 wsum
__device__ __forceinline__ void wprep_unit(int blk, int tid, const Params& p, float* tt /*32x33*/) {
    int tx = tid & 31, ty = tid >> 5;
    if (blk < 1536) {   // Wcat: logical [1024][1536] -> Wcat_t[1536][1024]
        int k0 = (blk & 31) * 32, n0 = (blk >> 5) * 32;
#pragma unroll
        for (int r = 0; r < 4; ++r) {
            int k = k0 + ty + r * 8;
            const float* s = (k < 512) ? p.Wioux + (size_t)k * 1536
                                       : p.Wiouh + (size_t)(k - 512) * 1536;
            tt[(ty + r * 8) * 33 + tx] = s[n0 + tx];
        }
        __syncthreads();
#pragma unroll
        for (int r = 0; r < 4; ++r)
            p.Wcat_t[(size_t)(n0 + ty + r * 8) * 1024 + k0 + tx] = f2bf(tt[tx * 33 + ty + r * 8]);
        return;
    }
    if (blk < 2176) {   // K=512 transposes -> [N][512]
        const float* W; ushort* Wt; int idx, ncols;
        if (blk < 1792)      { idx = blk - 1536; W = p.Wfh; Wt = p.Wfh_t; ncols = 512; }
        else if (blk < 2048) { idx = blk - 1792; W = p.Wfx; Wt = p.Wfx_t; ncols = 512; }
        else                 { idx = blk - 2048; W = p.Wwh; Wt = p.Wwh_t; ncols = 256; }
        int nt_count = ncols >> 5;
        int k0 = (idx / nt_count) * 32, n0 = (idx % nt_count) * 32;
#pragma unroll
        for (int r = 0; r < 4; ++r)
            tt[(ty + r * 8) * 33 + tx] = W[(size_t)(k0 + ty + r * 8) * ncols + n0 + tx];
        __syncthreads();
#pragma unroll
        for (int r = 0; r < 4; ++r)
            Wt[(size_t)(n0 + ty + r * 8) * 512 + k0 + tx] = f2bf(tt[tx * 33 + ty + r * 8]);
        return;
    }
    {   // wsum
        float s = 0.f;
        for (int o = 0; o < 30; ++o) s += p.Wwp[tid * 30 + o];
        p.wsum[tid] = s;
        if (tid == 0) {
            float t = 0.f;
            for (int o = 0; o < 30; ++o) t += p.bwp[o];
            p.wsum[256] = t;
        }
    }
}

// sm is [256][9] floats
__device__ __forceinline__ void gather_unit(int blk, int tid, const Params& p, float* sm) {
    int c = tid & 63, g = tid >> 6;
    float acc[8] = {};
    if (blk < 3584) {
        int s = blk >> 9, b = blk & 511;
        const int* aptr[7] = {p.q_v, p.qa0, p.na0, p.qa1, p.na1, p.qa2, p.na2};
        const int* ids = aptr[s] + b * 64 + g * 16;
        uint2 v[16];
#pragma unroll
        for (int t = 0; t < 16; ++t)
            v[t] = *(const uint2*)(p.emb8 + (size_t)ids[t] * 512 + c * 8);
#pragma unroll
        for (int t = 0; t < 16; ++t) { dec4_add(v[t].x, acc); dec4_add(v[t].y, acc + 4); }
#pragma unroll
        for (int k = 0; k < 8; ++k) sm[tid * 9 + k] = acc[k];
        __syncthreads();
        if (tid < 64) {
#pragma unroll
            for (int gg = 1; gg < 4; ++gg)
#pragma unroll
                for (int k = 0; k < 8; ++k) acc[k] += sm[(tid + gg * 64) * 9 + k];
            const float sc = 1.0f / (64.0f * FP8_SCALE);
            float* dst = p.pools + ((size_t)s * 512 + b) * 512 + tid * 8;
            *(float4*)dst = make_float4(acc[0] * sc, acc[1] * sc, acc[2] * sc, acc[3] * sc);
            *(float4*)(dst + 4) = make_float4(acc[4] * sc, acc[5] * sc, acc[6] * sc, acc[7] * sc);
        }
    } else {
        int idx = blk - 3584;
        int t = idx >> 11, rem = idx & 2047, b = rem >> 2, node = rem & 3;
        const int* sptr[3] = {p.query, p.pos, p.neg};
        const int* ids = sptr[t] + b * 128 + node * 32 + g * 8;
        uint2 v[8];
#pragma unroll
        for (int k = 0; k < 8; ++k)
            v[k] = *(const uint2*)(p.emb8 + (size_t)ids[k] * 512 + c * 8);
#pragma unroll
        for (int k = 0; k < 8; ++k) { dec4_add(v[k].x, acc); dec4_add(v[k].y, acc + 4); }
#pragma unroll
        for (int k = 0; k < 8; ++k) sm[tid * 9 + k] = acc[k];
        __syncthreads();
        if (tid < 64) {
#pragma unroll
            for (int gg = 1; gg < 4; ++gg)
#pragma unroll
                for (int k = 0; k < 8; ++k) acc[k] += sm[(tid + gg * 64) * 9 + k];
            const float sc = 1.0f / (32.0f * FP8_SCALE);
            short8 o;
#pragma unroll
            for (int k = 0; k < 8; ++k) o[k] = (short)f2bf(acc[k] * sc);
            if (node < 3) {
                size_t r = ((size_t)(t * 512 + b)) * 3 + node;
                *(short8*)(p.Xleaf + r * 512 + tid * 8) = o;
            } else {
                size_t r = (size_t)(t * 512 + b);
                *(short8*)(p.XR + r * 1024 + tid * 8) = o;
            }
        }
    }
}

__device__ __forceinline__ void dots_unit(int b, int tid, const Params& p, float* red /*6*4*/) {
    const float* pq = p.pools + (size_t)b * 512;
    float q0 = pq[tid], q1 = pq[tid + 256];
    float d[6];
#pragma unroll
    for (int a = 0; a < 6; ++a) {
        const float* pa = p.pools + ((size_t)(a + 1) * 512 + b) * 512;
        d[a] = q0 * pa[tid] + q1 * pa[tid + 256];
    }
    int lane = tid & 63, wid = tid >> 6;
#pragma unroll
    for (int a = 0; a < 6; ++a) {
        float v = d[a];
        for (int off = 32; off; off >>= 1) v += __shfl_down(v, off);
        if (lane == 0) red[a * 4 + wid] = v;
    }
    __syncthreads();
    if (tid == 0) {
        float l = 0.f;
#pragma unroll
        for (int i = 0; i < 3; ++i) {
            float dq = red[2*i*4] + red[2*i*4+1] + red[2*i*4+2] + red[2*i*4+3];
            float dn = red[(2*i+1)*4] + red[(2*i+1)*4+1] + red[(2*i+1)*4+2] + red[(2*i+1)*4+3];
            l += fmaxf(0.f, 1.f - dq + dn);
        }
        p.lossv[b] = l;
    }
}

// double-buffered 128x128xBK=32 bf16 MFMA GEMM tile, 4 waves x 64x64
__device__ inline void cstore(float* C, size_t idx, float v)  { C[idx] = v; }
__device__ inline void cstore(ushort* C, size_t idx, float v) { C[idx] = f2bf(v); }

template <typename OutT>
__device__ __forceinline__ void gemm_body(const ushort* A, int lda,
                                          const ushort* Bt, int ldb,
                                          OutT* C, int ldc, int K,
                                          int bx, int by, ushort* sA, ushort* sB) {
    int tid = threadIdx.x;
    int m0 = bx * 128, n0 = by * 128;
    int w = tid >> 6, lane = tid & 63;
    int wm = (w >> 1) * 64, wn = (w & 1) * 64;
    int l15 = lane & 15, g = lane >> 4;
    int srow = tid >> 2, scol = (tid & 3) * 8;

    const ushort* Ag0 = A + (size_t)(m0 + srow) * lda + scol;
    const ushort* Ag1 = A + (size_t)(m0 + srow + 64) * lda + scol;
    const ushort* Bg0 = Bt + (size_t)(n0 + srow) * ldb + scol;
    const ushort* Bg1 = Bt + (size_t)(n0 + srow + 64) * ldb + scol;

    floatx4 acc[4][4] = {};

    auto stage = [&](int buf, int kb) {
        ushort* dA = sA + buf * 4096;
        ushort* dB = sB + buf * 4096;
        GLD16(Ag0 + kb, dA + w * 512);
        GLD16(Ag1 + kb, dA + 2048 + w * 512);
        GLD16(Bg0 + kb, dB + w * 512);
        GLD16(Bg1 + kb, dB + 2048 + w * 512);
    };

    stage(0, 0);
    __syncthreads();
    int cur = 0;
    for (int kb = 0; kb < K; kb += 32) {
        if (kb + 32 < K) stage(cur ^ 1, kb + 32);
        const ushort* bA = sA + cur * 4096;
        const ushort* bB = sB + cur * 4096;
        short8 af[4], bf[4];
#pragma unroll
        for (int f = 0; f < 4; ++f) {
            af[f] = *(const short8*)(bA + (wm + f * 16 + l15) * 32 + g * 8);
            bf[f] = *(const short8*)(bB + (wn + f * 16 + l15) * 32 + g * 8);
        }
#pragma unroll
        for (int i = 0; i < 4; ++i)
#pragma unroll
            for (int j = 0; j < 4; ++j)
                acc[i][j] = __builtin_amdgcn_mfma_f32_16x16x32_bf16(af[i], bf[j], acc[i][j], 0, 0, 0);
        __syncthreads();
        cur ^= 1;
    }
    // C/D layout (HW-verified): col = lane&15, row = 4*(lane>>4)+reg
#pragma unroll
    for (int i = 0; i < 4; ++i)
#pragma unroll
        for (int j = 0; j < 4; ++j) {
            int row = m0 + wm + i * 16 + g * 4;
            int col = n0 + wn + j * 16 + l15;
#pragma unroll
            for (int r = 0; r < 4; ++r)
                cstore(C, (size_t)(row + r) * ldc + col, acc[i][j][r]);
        }
}

__device__ __forceinline__ void phase3_unit(int u, int tid, const Params& p, char* smem) {
    if (u < 432)
        gemm_body(p.Xleaf, 512, p.Wcat_t, 1024, p.IOU_l, 1536, 512, u % 36, u / 36,
                  (ushort*)smem, (ushort*)(smem + 16384));
    else
        dots_unit(u - 432, tid, p, (float*)smem);
}

__device__ __forceinline__ void phase5_unit(int u, const Params& p, char* smem) {
    ushort* sA = (ushort*)smem;
    ushort* sB = (ushort*)(smem + 16384);
    if (u < 144)
        gemm_body(p.XR, 1024, p.Wcat_t, 1024, p.IOU_r, 1536, 1024, u % 12, u / 12, sA, sB);
    else if (u < 288) {
        int q = u - 144;
        gemm_body(p.h_l, 512, p.Wfh_t, 512, p.FH, 512, 512, q % 36, q / 36, sA, sB);
    } else {
        int q = u - 288;
        gemm_body(p.XR, 1024, p.Wfx_t, 512, p.FX, 512, 512, q % 12, q / 12, sA, sB);
    }
}

__device__ __forceinline__ void leaf_unit(int tb, int tid, const Params& p) {
#pragma unroll
    for (int half = 0; half < 2; ++half) {
        int m = tid + half * 256;
        float bi = p.bioux[m] + p.biouh[m];
        float bo = p.bioux[m + 512] + p.biouh[m + 512];
        float bu = p.bioux[m + 1024] + p.biouh[m + 1024];
        float hs = 0.f;
#pragma unroll
        for (int leaf = 0; leaf < 3; ++leaf) {
            size_t r = (size_t)tb * 3 + leaf;
            const ushort* row = p.IOU_l + r * 1536;
            float iv = sigm(bf2f(row[m]) + bi);
            float ov = sigm(bf2f(row[m + 512]) + bo);
            float uv = tanhf(bf2f(row[m + 1024]) + bu);
            float c = iv * uv;
            p.c_l[r * 512 + m] = f2bf(c);
            float h = ov * tanhf(c);
            p.h_l[r * 512 + m] = f2bf(h);
            hs += h;
        }
        p.XR[(size_t)tb * 1024 + 512 + m] = f2bf(hs);
    }
}

__device__ __forceinline__ void root_unit(int r, int tid, const Params& p) {
#pragma unroll
    for (int half = 0; half < 2; ++half) {
        int m = tid + half * 256;
        float iv = sigm(bf2f(p.IOU_r[(size_t)r * 1536 + m]) + p.bioux[m] + p.biouh[m]);
        float uv = tanhf(bf2f(p.IOU_r[(size_t)r * 1536 + 1024 + m]) + p.bioux[1024 + m] + p.biouh[1024 + m]);
        float fx = bf2f(p.FX[(size_t)r * 512 + m]) + p.bfx[m];
        float c = iv * uv;
#pragma unroll
        for (int k = 0; k < 3; ++k) {
            size_t idx = ((size_t)r * 3 + k) * 512 + m;
            float f = sigm(bf2f(p.FH[idx]) + p.bfh[m] + fx);
            c += f * bf2f(p.c_l[idx]);
        }
        p.c_root[(size_t)r * 512 + m] = c;
    }
}

// sim GEMM: S[1024,256] = P @ Wwh, P rows built on the fly from c_root
__device__ __forceinline__ void sim_unit(int blk, int tid, const Params& p, char* smem) {
    ushort* sA = (ushort*)smem;
    ushort* sB = (ushort*)(smem + 16384);
    int bx = blk & 7, by = blk >> 3;
    int m0 = bx * 128, n0 = by * 128;
    int w = tid >> 6, lane = tid & 63;
    int wm = (w >> 1) * 64, wn = (w & 1) * 64;
    int l15 = lane & 15, g = lane >> 4;
    int srow = tid >> 2, scol = (tid & 3) * 8;

    const ushort* Bg0 = p.Wwh_t + (size_t)(n0 + srow) * 512 + scol;
    const ushort* Bg1 = p.Wwh_t + (size_t)(n0 + srow + 64) * 512 + scol;

    floatx4 acc[4][4] = {};

    auto stage = [&](int buf, int kb) {
        ushort* dA = sA + buf * 4096;
        ushort* dB = sB + buf * 4096;
        GLD16(Bg0 + kb, dB + w * 512);
        GLD16(Bg1 + kb, dB + 2048 + w * 512);
#pragma unroll
        for (int half = 0; half < 2; ++half) {
            int gr = m0 + srow + half * 64;
            int b = gr & 511, which = gr >> 9;
            const float* qrow = p.c_root + (size_t)b * 512 + kb + scol;
            const float* orow = p.c_root + ((size_t)(which + 1) * 512 + b) * 512 + kb + scol;
            float4 q0 = *(const float4*)qrow, q1 = *(const float4*)(qrow + 4);
            float4 o0 = *(const float4*)orow, o1 = *(const float4*)(orow + 4);
            short8 pv;
            pv[0] = (short)f2bf(q0.x * o0.x); pv[1] = (short)f2bf(q0.y * o0.y);
            pv[2] = (short)f2bf(q0.z * o0.z); pv[3] = (short)f2bf(q0.w * o0.w);
            pv[4] = (short)f2bf(q1.x * o1.x); pv[5] = (short)f2bf(q1.y * o1.y);
            pv[6] = (short)f2bf(q1.z * o1.z); pv[7] = (short)f2bf(q1.w * o1.w);
            *(short8*)(dA + (srow + half * 64) * 32 + scol) = pv;
        }
    };

    stage(0, 0);
    __syncthreads();
    int cur = 0;
    for (int kb = 0; kb < 512; kb += 32) {
        if (kb + 32 < 512) stage(cur ^ 1, kb + 32);
        const ushort* bA = sA + cur * 4096;
        const ushort* bB = sB + cur * 4096;
        short8 af[4], bf[4];
#pragma unroll
        for (int f = 0; f < 4; ++f) {
            af[f] = *(const short8*)(bA + (wm + f * 16 + l15) * 32 + g * 8);
            bf[f] = *(const short8*)(bB + (wn + f * 16 + l15) * 32 + g * 8);
        }
#pragma unroll
        for (int i = 0; i < 4; ++i)
#pragma unroll
            for (int j = 0; j < 4; ++j)
                acc[i][j] = __builtin_amdgcn_mfma_f32_16x16x32_bf16(af[i], bf[j], acc[i][j], 0, 0, 0);
        __syncthreads();
        cur ^= 1;
    }
#pragma unroll
    for (int i = 0; i < 4; ++i)
#pragma unroll
        for (int j = 0; j < 4; ++j) {
            int row = m0 + wm + i * 16 + g * 4;
            int col = n0 + wn + j * 16 + l15;
#pragma unroll
            for (int r = 0; r < 4; ++r)
                p.S[(size_t)(row + r) * 256 + col] = acc[i][j][r];
        }
}

__device__ __forceinline__ void final_unit(int b, int tid, const Params& p, float* red /*2*4*/) {
    float w = p.wsum[tid];
    float bw = p.bwh[tid];
    float va = sigm(p.S[(size_t)b * 256 + tid] + bw) * w;
    float vb = sigm(p.S[(size_t)(512 + b) * 256 + tid] + bw) * w;
    int lane = tid & 63, wid = tid >> 6;
    for (int off = 32; off; off >>= 1) {
        va += __shfl_down(va, off);
        vb += __shfl_down(vb, off);
    }
    if (lane == 0) { red[wid] = va; red[4 + wid] = vb; }
    __syncthreads();
    if (tid == 0) {
        float a  = red[0] + red[1] + red[2] + red[3] + p.wsum[256];
        float bb = red[4] + red[5] + red[6] + red[7] + p.wsum[256];
        p.out[b] = p.lossv[b] + fmaxf(0.f, 1.f - a + bb);
    }
}

// ---------------- cooperative mega kernel ----------------

__global__ __launch_bounds__(256, 2) void mega_kernel(Params p) {
    cg::grid_group grid = cg::this_grid();
    __shared__ __align__(16) char smem[32768];
    float* smf = (float*)smem;
    int tid = threadIdx.x;
    int nblk = p.nblk;

    for (int u = blockIdx.x; u < N_CONV; u += nblk) conv_unit(u, tid, p);
    grid.sync();
    for (int u = blockIdx.x; u < N_PH2; u += nblk) {
        if (u < N_GATHER) gather_unit(u, tid, p, smf);
        else              wprep_unit(u - N_GATHER, tid, p, smf);
        __syncthreads();
    }
    grid.sync();
    for (int u = blockIdx.x; u < N_PH3; u += nblk) {
        phase3_unit(u, tid, p, smem);
        __syncthreads();
    }
    grid.sync();
    for (int u = blockIdx.x; u < N_LEAF; u += nblk) leaf_unit(u, tid, p);
    grid.sync();
    for (int u = blockIdx.x; u < N_GEMM3; u += nblk) {
        phase5_unit(u, p, smem);
        __syncthreads();
    }
    grid.sync();
    for (int u = blockIdx.x; u < N_ROOT; u += nblk) root_unit(u, tid, p);
    grid.sync();
    for (int u = blockIdx.x; u < N_SIM; u += nblk) {
        sim_unit(u, tid, p, smem);
        __syncthreads();
    }
    grid.sync();
    for (int u = blockIdx.x; u < N_FINAL; u += nblk) {
        final_unit(u, tid, p, smf);
        __syncthreads();
    }
}

// ---------------- fallback wrappers (proven round-4 chain) ----------------

__global__ __launch_bounds__(256) void conv_kernel(Params p) {
    conv_unit(blockIdx.x, threadIdx.x, p);
}
__global__ __launch_bounds__(256) void gatherprep_kernel(Params p) {
    __shared__ float sm[256 * 9];
    int u = blockIdx.x;
    if (u < N_GATHER) gather_unit(u, threadIdx.x, p, sm);
    else              wprep_unit(u - N_GATHER, threadIdx.x, p, sm);
}
__global__ __launch_bounds__(256) void g1dots_kernel(Params p) {
    __shared__ __align__(16) char smem[32768];
    phase3_unit(blockIdx.x, threadIdx.x, p, smem);
}
__global__ __launch_bounds__(256) void leaf_kernel(Params p) {
    leaf_unit(blockIdx.x, threadIdx.x, p);
}
__global__ __launch_bounds__(256) void gemm3_kernel(Params p) {
    __shared__ __align__(16) char smem[32768];
    phase5_unit(blockIdx.x, p, smem);
}
__global__ __launch_bounds__(256) void root_kernel(Params p) {
    root_unit(blockIdx.x, threadIdx.x, p);
}
__global__ __launch_bounds__(256) void sim_kernel(Params p) {
    __shared__ __align__(16) char smem[32768];
    sim_unit(blockIdx.x, threadIdx.x, p, smem);
}
__global__ __launch_bounds__(256) void final_kernel_w(Params p) {
    __shared__ float red[8];
    final_unit(blockIdx.x, threadIdx.x, p, red);
}

// ---------------- launch ----------------

extern "C" void kernel_launch(void* const* d_in, const int* in_sizes, int n_in,
                              void* d_out, int out_size, void* d_ws, size_t ws_size,
                              hipStream_t stream) {
    Params prm;
    prm.q_v   = (const int*)d_in[0];
    prm.qa0   = (const int*)d_in[1];
    prm.na0   = (const int*)d_in[2];
    prm.qa1   = (const int*)d_in[3];
    prm.na1   = (const int*)d_in[4];
    prm.qa2   = (const int*)d_in[5];
    prm.na2   = (const int*)d_in[6];
    prm.query = (const int*)d_in[7];
    prm.pos   = (const int*)d_in[8];
    prm.neg   = (const int*)d_in[9];
    prm.emb   = (const float*)d_in[10];
    prm.Wioux = (const float*)d_in[11];
    prm.bioux = (const float*)d_in[12];
    prm.Wiouh = (const float*)d_in[13];
    prm.biouh = (const float*)d_in[14];
    prm.Wfx   = (const float*)d_in[15];
    prm.bfx   = (const float*)d_in[16];
    prm.Wfh   = (const float*)d_in[17];
    prm.bfh   = (const float*)d_in[18];
    prm.Wwh   = (const float*)d_in[19];
    prm.bwh   = (const float*)d_in[20];
    prm.Wwp   = (const float*)d_in[21];
    prm.bwp   = (const float*)d_in[22];
    prm.out   = (float*)d_out;

    char* w = (char*)d_ws;
    size_t off = 0;
    auto alloc = [&](size_t bytes) -> void* {
        void* ptr = (void*)(w + off);
        off = (off + bytes + 255) & ~(size_t)255;
        return ptr;
    };
    // ---- persistent region ----
    prm.Wcat_t = (ushort*)alloc((size_t)1536 * 1024 * 2);
    prm.Wfh_t  = (ushort*)alloc((size_t)512 * 512 * 2);
    prm.Wfx_t  = (ushort*)alloc((size_t)512 * 512 * 2);
    prm.Wwh_t  = (ushort*)alloc((size_t)256 * 512 * 2);
    prm.wsum   = (float*) alloc(257 * 4);
    prm.lossv  = (float*) alloc(512 * 4);
    prm.Xleaf  = (ushort*)alloc((size_t)4608 * 512 * 2);
    prm.XR     = (ushort*)alloc((size_t)1536 * 1024 * 2);
    // ---- aliased region: phase1-3 (emb8, pools) overlapped by later temporaries.
    // Safe by phase ordering: emb8 dead after gather; pools dead after dots.
    size_t xbase = off;
    prm.emb8  = (unsigned char*)alloc((size_t)50000 * 512);
    prm.pools = (float*)        alloc((size_t)7 * 512 * 512 * 4);
    off = xbase;  // rewind
    prm.IOU_l  = (ushort*)alloc((size_t)4608 * 1536 * 2);
    prm.c_l    = (ushort*)alloc((size_t)4608 * 512 * 2);
    prm.h_l    = (ushort*)alloc((size_t)4608 * 512 * 2);
    prm.FH     = (ushort*)alloc((size_t)4608 * 512 * 2);
    prm.FX     = (ushort*)alloc((size_t)1536 * 512 * 2);
    prm.IOU_r  = (ushort*)alloc((size_t)1536 * 1536 * 2);
    prm.c_root = (float*) alloc((size_t)1536 * 512 * 4);
    prm.S      = (float*) alloc((size_t)1024 * 256 * 4);

    // runtime-sized cooperative launch (no capacity assumptions)
    int dev = 0;
    (void)hipGetDevice(&dev);
    int maxPerCU = 0, nCU = 0;
    (void)hipOccupancyMaxActiveBlocksPerMultiprocessor(&maxPerCU, (const void*)mega_kernel, 256, 0);
    (void)hipDeviceGetAttribute(&nCU, hipDeviceAttributeMultiprocessorCount, dev);

    hipError_t err = hipErrorUnknown;
    if (maxPerCU > 0 && nCU > 0) {
        int nblk = maxPerCU * nCU;
        if (nblk > 2048) nblk = 2048;
        prm.nblk = nblk;
        void* args[] = {&prm};
        err = hipLaunchCooperativeKernel((const void*)mega_kernel, dim3(nblk), dim3(256),
                                         args, 0, stream);
    }
    if (err != hipSuccess) {
        (void)hipGetLastError();  // clear sticky error from the failed coop attempt
        prm.nblk = 0;
        conv_kernel<<<N_CONV, 256, 0, stream>>>(prm);
        gatherprep_kernel<<<N_PH2, 256, 0, stream>>>(prm);
        g1dots_kernel<<<N_PH3, 256, 0, stream>>>(prm);
        leaf_kernel<<<N_LEAF, 256, 0, stream>>>(prm);
        gemm3_kernel<<<N_GEMM3, 256, 0, stream>>>(prm);
        root_kernel<<<N_ROOT, 256, 0, stream>>>(prm);
        sim_kernel<<<N_SIM, 256, 0, stream>>>(prm);
        final_kernel_w<<<N_FINAL, 256, 0, stream>>>(prm);
    }
}

// Round 7
// 123.459 us; speedup vs baseline: 3.2520x; 3.2520x over previous
//
#include <hip/hip_runtime.h>
#include <hip/hip_bf16.h>

// FEELModel: fp8 emb table + fused gathers (fp32 accum); TreeLSTM + sim head via bf16 MFMA.
// Round-4 proven 8-kernel chain + LDS chunk-XOR swizzle in all GEMMs
// (linear global_load_lds dest + pre-swizzled global source + swizzled read — rule #21).
// B=512, L=64, Lq=128, D=M=512, 3M=1536, H=256, O=30

typedef __attribute__((ext_vector_type(8))) short short8;   // 8 bf16
typedef __attribute__((ext_vector_type(4))) float floatx4;  // MFMA C/D frag
typedef __attribute__((ext_vector_type(2))) float floatx2;

__device__ inline ushort f2bf(float f) {            // fp32 -> bf16 bits, RNE
    unsigned u = __float_as_uint(f);
    u += 0x7fffu + ((u >> 16) & 1u);
    return (ushort)(u >> 16);
}
__device__ inline float bf2f(ushort u) { return __uint_as_float((unsigned)u << 16); }
__device__ inline float sigm(float x) { return 1.0f / (1.0f + expf(-x)); }

#if defined(__has_builtin)
#if __has_builtin(__builtin_amdgcn_cvt_pk_f32_fp8) && __has_builtin(__builtin_amdgcn_cvt_pk_fp8_f32)
#define HW_FP8 1
#endif
#endif

#ifndef HW_FP8
__device__ inline unsigned enc1(float x) {          // manual e4m3fn encode, RNE, saturating
    float a = fabsf(x);
    unsigned s = (__float_as_uint(x) >> 31) << 7;
    unsigned b = __float_as_uint(a);
    unsigned uexp = b >> 23;
    if (uexp < 121) {
        int m = (int)(a * 512.0f + 0.5f);
        if (m >= 8) return s | 0x08u;
        return s | (unsigned)m;
    }
    b += 0x00080000u;
    unsigned e = b >> 23;
    if (e > 135u) return s | 0x7Eu;
    return s | ((e - 120u) << 3) | ((b >> 20) & 7u);
}
__device__ inline float dec1(unsigned v) {
    unsigned s = (v >> 7) & 1u, e = (v >> 3) & 15u, m = v & 7u;
    float r = e ? __uint_as_float(((e + 120u) << 23) | (m << 20))
                : (float)m * 0.001953125f;
    return s ? -r : r;
}
#endif

__device__ inline unsigned pk4(float a, float b, float c, float d) {
#ifdef HW_FP8
    int v = 0;
    v = __builtin_amdgcn_cvt_pk_fp8_f32(a, b, v, false);
    v = __builtin_amdgcn_cvt_pk_fp8_f32(c, d, v, true);
    return (unsigned)v;
#else
    return enc1(a) | (enc1(b) << 8) | (enc1(c) << 16) | (enc1(d) << 24);
#endif
}
__device__ inline void dec4_add(unsigned v, float* acc) {
#ifdef HW_FP8
    floatx2 p0 = __builtin_amdgcn_cvt_pk_f32_fp8(v, false);
    floatx2 p1 = __builtin_amdgcn_cvt_pk_f32_fp8(v, true);
    acc[0] += p0[0]; acc[1] += p0[1]; acc[2] += p1[0]; acc[3] += p1[1];
#else
    acc[0] += dec1(v & 255u); acc[1] += dec1((v >> 8) & 255u);
    acc[2] += dec1((v >> 16) & 255u); acc[3] += dec1(v >> 24);
#endif
}

#define GLD16(gp, sp)                                                        \
    __builtin_amdgcn_global_load_lds(                                        \
        (const __attribute__((address_space(1))) unsigned int*)(const void*)(gp), \
        (__attribute__((address_space(3))) unsigned int*)(void*)(sp), 16, 0, 0)

#define FP8_SCALE 64.0f

// ---------------- mega prep: emb->fp8, coalesced transposes, wsum ----------------
__global__ __launch_bounds__(256) void prep_all_kernel(
    const float* __restrict__ emb, unsigned char* __restrict__ emb8,
    const float* __restrict__ Wioux, const float* __restrict__ Wiouh,
    const float* __restrict__ Wfh, const float* __restrict__ Wfx,
    const float* __restrict__ Wwh, const float* __restrict__ Wwp,
    const float* __restrict__ bwp,
    ushort* __restrict__ Wcat_t, ushort* __restrict__ Wfh_t,
    ushort* __restrict__ Wfx_t, ushort* __restrict__ Wwh_t,
    float* __restrict__ wsum) {
    __shared__ float tt[32][33];
    int blk = blockIdx.x, tid = threadIdx.x;
    if (blk < 12500) {
        size_t i = ((size_t)blk * 256 + tid) * 8;
        float4 a = *(const float4*)(emb + i);
        float4 b = *(const float4*)(emb + i + 4);
        uint2 o;
        o.x = pk4(a.x * FP8_SCALE, a.y * FP8_SCALE, a.z * FP8_SCALE, a.w * FP8_SCALE);
        o.y = pk4(b.x * FP8_SCALE, b.y * FP8_SCALE, b.z * FP8_SCALE, b.w * FP8_SCALE);
        *(uint2*)(emb8 + i) = o;
        return;
    }
    int tx = tid & 31, ty = tid >> 5;
    if (blk < 14036) {  // Wcat: logical [1024][1536] -> Wcat_t[1536][1024]
        int idx = blk - 12500;
        int k0 = (idx & 31) * 32, n0 = (idx >> 5) * 32;
#pragma unroll
        for (int r = 0; r < 4; ++r) {
            int k = k0 + ty + r * 8;
            const float* s = (k < 512) ? Wioux + (size_t)k * 1536
                                       : Wiouh + (size_t)(k - 512) * 1536;
            tt[ty + r * 8][tx] = s[n0 + tx];
        }
        __syncthreads();
#pragma unroll
        for (int r = 0; r < 4; ++r)
            Wcat_t[(size_t)(n0 + ty + r * 8) * 1024 + k0 + tx] = f2bf(tt[tx][ty + r * 8]);
        return;
    }
    if (blk < 14676) {  // K=512 transposes -> [N][512]
        const float* W; ushort* Wt; int idx, ncols;
        if (blk < 14292)      { idx = blk - 14036; W = Wfh; Wt = Wfh_t; ncols = 512; }
        else if (blk < 14548) { idx = blk - 14292; W = Wfx; Wt = Wfx_t; ncols = 512; }
        else                  { idx = blk - 14548; W = Wwh; Wt = Wwh_t; ncols = 256; }
        int nt_count = ncols >> 5;
        int k0 = (idx / nt_count) * 32, n0 = (idx % nt_count) * 32;
#pragma unroll
        for (int r = 0; r < 4; ++r)
            tt[ty + r * 8][tx] = W[(size_t)(k0 + ty + r * 8) * ncols + n0 + tx];
        __syncthreads();
#pragma unroll
        for (int r = 0; r < 4; ++r)
            Wt[(size_t)(n0 + ty + r * 8) * 512 + k0 + tx] = f2bf(tt[tx][ty + r * 8]);
        return;
    }
    {
        float s = 0.f;
        for (int o = 0; o < 30; ++o) s += Wwp[tid * 30 + o];
        wsum[tid] = s;
        if (tid == 0) {
            float t = 0.f;
            for (int o = 0; o < 30; ++o) t += bwp[o];
            wsum[256] = t;
        }
    }
}

// ---------------- mega gather (fp8 table, batch-loads-then-decode) ----------------
__global__ __launch_bounds__(256) void mega_gather_kernel(
    const int* __restrict__ q_v,
    const int* __restrict__ qa0, const int* __restrict__ na0,
    const int* __restrict__ qa1, const int* __restrict__ na1,
    const int* __restrict__ qa2, const int* __restrict__ na2,
    const int* __restrict__ query, const int* __restrict__ pos, const int* __restrict__ neg,
    const unsigned char* __restrict__ emb8,
    float* __restrict__ pools, ushort* __restrict__ Xleaf, ushort* __restrict__ XR) {
    __shared__ float sm[256][9];
    int tid = threadIdx.x;
    int c = tid & 63, g = tid >> 6;
    float acc[8] = {};
    if (blockIdx.x < 3584) {
        int s = blockIdx.x >> 9, b = blockIdx.x & 511;
        const int* aptr[7] = {q_v, qa0, na0, qa1, na1, qa2, na2};
        const int* ids = aptr[s] + b * 64 + g * 16;
        uint2 v[16];
#pragma unroll
        for (int t = 0; t < 16; ++t)
            v[t] = *(const uint2*)(emb8 + (size_t)ids[t] * 512 + c * 8);
#pragma unroll
        for (int t = 0; t < 16; ++t) { dec4_add(v[t].x, acc); dec4_add(v[t].y, acc + 4); }
#pragma unroll
        for (int k = 0; k < 8; ++k) sm[tid][k] = acc[k];
        __syncthreads();
        if (tid < 64) {
#pragma unroll
            for (int gg = 1; gg < 4; ++gg)
#pragma unroll
                for (int k = 0; k < 8; ++k) acc[k] += sm[tid + gg * 64][k];
            const float sc = 1.0f / (64.0f * FP8_SCALE);
            float* dst = pools + ((size_t)s * 512 + b) * 512 + tid * 8;
            *(float4*)dst = make_float4(acc[0] * sc, acc[1] * sc, acc[2] * sc, acc[3] * sc);
            *(float4*)(dst + 4) = make_float4(acc[4] * sc, acc[5] * sc, acc[6] * sc, acc[7] * sc);
        }
    } else {
        int idx = blockIdx.x - 3584;
        int t = idx >> 11, rem = idx & 2047, b = rem >> 2, node = rem & 3;
        const int* sptr[3] = {query, pos, neg};
        const int* ids = sptr[t] + b * 128 + node * 32 + g * 8;
        uint2 v[8];
#pragma unroll
        for (int k = 0; k < 8; ++k)
            v[k] = *(const uint2*)(emb8 + (size_t)ids[k] * 512 + c * 8);
#pragma unroll
        for (int k = 0; k < 8; ++k) { dec4_add(v[k].x, acc); dec4_add(v[k].y, acc + 4); }
#pragma unroll
        for (int k = 0; k < 8; ++k) sm[tid][k] = acc[k];
        __syncthreads();
        if (tid < 64) {
#pragma unroll
            for (int gg = 1; gg < 4; ++gg)
#pragma unroll
                for (int k = 0; k < 8; ++k) acc[k] += sm[tid + gg * 64][k];
            const float sc = 1.0f / (32.0f * FP8_SCALE);
            short8 o;
#pragma unroll
            for (int k = 0; k < 8; ++k) o[k] = (short)f2bf(acc[k] * sc);
            if (node < 3) {
                size_t r = ((size_t)(t * 512 + b)) * 3 + node;
                *(short8*)(Xleaf + r * 512 + tid * 8) = o;
            } else {
                size_t r = (size_t)(t * 512 + b);
                *(short8*)(XR + r * 1024 + tid * 8) = o;
            }
        }
    }
}

// ---------------- bf16 MFMA GEMM body (double-buffered, swizzled LDS) ----------------
// 128x128 tile, BK=32, 4 waves each 64x64. LDS rows are 32 ushorts (64 B); the 16 B
// chunk of global k-space g for row r sits at LDS chunk g ^ ((r>>1)&3). Write side:
// linear gload_lds dest + source chunk csw = (tid&3) ^ ((tid>>3)&3). Read side:
// chunk crd = g ^ ((l15>>1)&3). XOR involution -> MFMA data identical to unswizzled;
// read bank slots 8-way -> 2-way (free, m136).
__device__ inline void cstore(float* C, size_t idx, float v)  { C[idx] = v; }
__device__ inline void cstore(ushort* C, size_t idx, float v) { C[idx] = f2bf(v); }

template <typename OutT>
__device__ __forceinline__ void gemm_body(const ushort* __restrict__ A, int lda,
                                          const ushort* __restrict__ Bt, int ldb,
                                          OutT* __restrict__ C, int ldc, int K,
                                          int bx, int by, ushort* sA, ushort* sB) {
    int tid = threadIdx.x;
    int m0 = bx * 128, n0 = by * 128;
    int w = tid >> 6, lane = tid & 63;
    int wm = (w >> 1) * 64, wn = (w & 1) * 64;
    int l15 = lane & 15, g = lane >> 4;
    int srow = tid >> 2;
    int csw = (((tid & 3) ^ ((tid >> 3) & 3))) * 8;   // swizzled source chunk (elems)
    int crd = (g ^ ((l15 >> 1) & 3)) * 8;             // swizzled read chunk (elems)

    const ushort* Ag0 = A + (size_t)(m0 + srow) * lda + csw;
    const ushort* Ag1 = A + (size_t)(m0 + srow + 64) * lda + csw;
    const ushort* Bg0 = Bt + (size_t)(n0 + srow) * ldb + csw;
    const ushort* Bg1 = Bt + (size_t)(n0 + srow + 64) * ldb + csw;

    floatx4 acc[4][4] = {};

    auto stage = [&](int buf, int kb) {
        ushort* dA = sA + buf * 4096;
        ushort* dB = sB + buf * 4096;
        GLD16(Ag0 + kb, dA + w * 512);
        GLD16(Ag1 + kb, dA + 2048 + w * 512);
        GLD16(Bg0 + kb, dB + w * 512);
        GLD16(Bg1 + kb, dB + 2048 + w * 512);
    };

    stage(0, 0);
    __syncthreads();
    int cur = 0;
    for (int kb = 0; kb < K; kb += 32) {
        if (kb + 32 < K) stage(cur ^ 1, kb + 32);
        const ushort* bA = sA + cur * 4096;
        const ushort* bB = sB + cur * 4096;
        short8 af[4], bf[4];
#pragma unroll
        for (int f = 0; f < 4; ++f) {
            af[f] = *(const short8*)(bA + (wm + f * 16 + l15) * 32 + crd);
            bf[f] = *(const short8*)(bB + (wn + f * 16 + l15) * 32 + crd);
        }
#pragma unroll
        for (int i = 0; i < 4; ++i)
#pragma unroll
            for (int j = 0; j < 4; ++j)
                acc[i][j] = __builtin_amdgcn_mfma_f32_16x16x32_bf16(af[i], bf[j], acc[i][j], 0, 0, 0);
        __syncthreads();
        cur ^= 1;
    }
    // C/D layout (HW-verified): col = lane&15, row = 4*(lane>>4)+reg
#pragma unroll
    for (int i = 0; i < 4; ++i)
#pragma unroll
        for (int j = 0; j < 4; ++j) {
            int row = m0 + wm + i * 16 + g * 4;
            int col = n0 + wn + j * 16 + l15;
#pragma unroll
            for (int r = 0; r < 4; ++r)
                cstore(C, (size_t)(row + r) * ldc + col, acc[i][j][r]);
        }
}

// G1 (leaf IOU, 432 blocks) + dots (512 blocks) in one launch
__global__ __launch_bounds__(256) void g1_dots_kernel(
    const ushort* __restrict__ Xleaf, const ushort* __restrict__ Wcat_t,
    ushort* __restrict__ IOU_l,
    const float* __restrict__ pools, float* __restrict__ lossv) {
    __shared__ alignas(16) ushort sA[8192];
    __shared__ alignas(16) ushort sB[8192];
    __shared__ float red[6][4];
    int blk = blockIdx.x, tid = threadIdx.x;
    if (blk < 432) {
        gemm_body(Xleaf, 512, Wcat_t, 1024, IOU_l, 1536, 512, blk % 36, blk / 36, sA, sB);
        return;
    }
    int b = blk - 432;
    const float* pq = pools + (size_t)b * 512;
    float q0 = pq[tid], q1 = pq[tid + 256];
    float d[6];
#pragma unroll
    for (int a = 0; a < 6; ++a) {
        const float* pa = pools + ((size_t)(a + 1) * 512 + b) * 512;
        d[a] = q0 * pa[tid] + q1 * pa[tid + 256];
    }
    int lane = tid & 63, wid = tid >> 6;
#pragma unroll
    for (int a = 0; a < 6; ++a) {
        float v = d[a];
        for (int off = 32; off; off >>= 1) v += __shfl_down(v, off);
        if (lane == 0) red[a][wid] = v;
    }
    __syncthreads();
    if (tid == 0) {
        float l = 0.f;
#pragma unroll
        for (int i = 0; i < 3; ++i) {
            float dq = red[2*i][0] + red[2*i][1] + red[2*i][2] + red[2*i][3];
            float dn = red[2*i+1][0] + red[2*i+1][1] + red[2*i+1][2] + red[2*i+1][3];
            l += fmaxf(0.f, 1.f - dq + dn);
        }
        lossv[b] = l;
    }
}

// G4 (IOU_r, K=1024, blocks 0-143 — longest first) + G2 (FH, 144-287) + G3 (FX, 288-335)
__global__ __launch_bounds__(256) void gemm3_kernel(
    const ushort* __restrict__ h_l, const ushort* __restrict__ XR,
    const ushort* __restrict__ Wfh_t, const ushort* __restrict__ Wfx_t,
    const ushort* __restrict__ Wcat_t,
    ushort* __restrict__ FH, ushort* __restrict__ FX, ushort* __restrict__ IOU_r) {
    __shared__ alignas(16) ushort sA[8192];
    __shared__ alignas(16) ushort sB[8192];
    int r = blockIdx.x;
    if (r < 144)      gemm_body(XR, 1024, Wcat_t, 1024, IOU_r, 1536, 1024, r % 12, r / 12, sA, sB);
    else if (r < 288) { int q = r - 144; gemm_body(h_l, 512, Wfh_t, 512, FH, 512, 512, q % 36, q / 36, sA, sB); }
    else              { int q = r - 288; gemm_body(XR, 1024, Wfx_t, 512, FX, 512, 512, q % 12, q / 12, sA, sB); }
}

// sim GEMM: S[1024,256] = P @ Wwh, P rows built on the fly from c_root.
// A staged via reg+ds_write (linear dest chunk, swizzled source chunk); B via gload_lds.
__global__ __launch_bounds__(256) void gemm_sim_kernel(
    const float* __restrict__ c_root, const ushort* __restrict__ Wwh_t,
    float* __restrict__ S) {
    __shared__ alignas(16) ushort sA[8192];
    __shared__ alignas(16) ushort sB[8192];
    int tid = threadIdx.x;
    int bx = blockIdx.x & 7, by = blockIdx.x >> 3;
    int m0 = bx * 128, n0 = by * 128;
    int w = tid >> 6, lane = tid & 63;
    int wm = (w >> 1) * 64, wn = (w & 1) * 64;
    int l15 = lane & 15, g = lane >> 4;
    int srow = tid >> 2;
    int csw = (((tid & 3) ^ ((tid >> 3) & 3))) * 8;
    int crd = (g ^ ((l15 >> 1) & 3)) * 8;

    const ushort* Bg0 = Wwh_t + (size_t)(n0 + srow) * 512 + csw;
    const ushort* Bg1 = Wwh_t + (size_t)(n0 + srow + 64) * 512 + csw;

    floatx4 acc[4][4] = {};

    auto stage = [&](int buf, int kb) {
        ushort* dA = sA + buf * 4096;
        ushort* dB = sB + buf * 4096;
        GLD16(Bg0 + kb, dB + w * 512);
        GLD16(Bg1 + kb, dB + 2048 + w * 512);
#pragma unroll
        for (int half = 0; half < 2; ++half) {
            int gr = m0 + srow + half * 64;
            int b = gr & 511, which = gr >> 9;
            const float* qrow = c_root + (size_t)b * 512 + kb + csw;
            const float* orow = c_root + ((size_t)(which + 1) * 512 + b) * 512 + kb + csw;
            float4 q0 = *(const float4*)qrow, q1 = *(const float4*)(qrow + 4);
            float4 o0 = *(const float4*)orow, o1 = *(const float4*)(orow + 4);
            short8 pv;
            pv[0] = (short)f2bf(q0.x * o0.x); pv[1] = (short)f2bf(q0.y * o0.y);
            pv[2] = (short)f2bf(q0.z * o0.z); pv[3] = (short)f2bf(q0.w * o0.w);
            pv[4] = (short)f2bf(q1.x * o1.x); pv[5] = (short)f2bf(q1.y * o1.y);
            pv[6] = (short)f2bf(q1.z * o1.z); pv[7] = (short)f2bf(q1.w * o1.w);
            *(short8*)(dA + (srow + half * 64) * 32 + (tid & 3) * 8) = pv;
        }
    };

    stage(0, 0);
    __syncthreads();
    int cur = 0;
    for (int kb = 0; kb < 512; kb += 32) {
        if (kb + 32 < 512) stage(cur ^ 1, kb + 32);
        const ushort* bA = sA + cur * 4096;
        const ushort* bB = sB + cur * 4096;
        short8 af[4], bf[4];
#pragma unroll
        for (int f = 0; f < 4; ++f) {
            af[f] = *(const short8*)(bA + (wm + f * 16 + l15) * 32 + crd);
            bf[f] = *(const short8*)(bB + (wn + f * 16 + l15) * 32 + crd);
        }
#pragma unroll
        for (int i = 0; i < 4; ++i)
#pragma unroll
            for (int j = 0; j < 4; ++j)
                acc[i][j] = __builtin_amdgcn_mfma_f32_16x16x32_bf16(af[i], bf[j], acc[i][j], 0, 0, 0);
        __syncthreads();
        cur ^= 1;
    }
#pragma unroll
    for (int i = 0; i < 4; ++i)
#pragma unroll
        for (int j = 0; j < 4; ++j) {
            int row = m0 + wm + i * 16 + g * 4;
            int col = n0 + wn + j * 16 + l15;
#pragma unroll
            for (int r = 0; r < 4; ++r)
                S[(size_t)(row + r) * 256 + col] = acc[i][j][r];
        }
}

// ---------------- TreeLSTM epilogues (bf16 in/out) ----------------

__global__ __launch_bounds__(256) void leaf_act_kernel(
    const ushort* __restrict__ IOU_l, const float* __restrict__ bioux,
    const float* __restrict__ biouh, ushort* __restrict__ c_l,
    ushort* __restrict__ h_l, ushort* __restrict__ XR) {
    int tb = blockIdx.x, tid = threadIdx.x;
#pragma unroll
    for (int half = 0; half < 2; ++half) {
        int m = tid + half * 256;
        float bi = bioux[m] + biouh[m];
        float bo = bioux[m + 512] + biouh[m + 512];
        float bu = bioux[m + 1024] + biouh[m + 1024];
        float hs = 0.f;
#pragma unroll
        for (int leaf = 0; leaf < 3; ++leaf) {
            size_t r = (size_t)tb * 3 + leaf;
            const ushort* row = IOU_l + r * 1536;
            float iv = sigm(bf2f(row[m]) + bi);
            float ov = sigm(bf2f(row[m + 512]) + bo);
            float uv = tanhf(bf2f(row[m + 1024]) + bu);
            float c = iv * uv;
            c_l[r * 512 + m] = f2bf(c);
            float h = ov * tanhf(c);
            h_l[r * 512 + m] = f2bf(h);
            hs += h;
        }
        XR[(size_t)tb * 1024 + 512 + m] = f2bf(hs);
    }
}

__global__ __launch_bounds__(256) void root_act_kernel(
    const ushort* __restrict__ IOU_r, const ushort* __restrict__ FH,
    const ushort* __restrict__ FX, const ushort* __restrict__ c_l,
    const float* __restrict__ bioux, const float* __restrict__ biouh,
    const float* __restrict__ bfx, const float* __restrict__ bfh,
    float* __restrict__ c_root) {
    int r = blockIdx.x, tid = threadIdx.x;
#pragma unroll
    for (int half = 0; half < 2; ++half) {
        int m = tid + half * 256;
        float iv = sigm(bf2f(IOU_r[(size_t)r * 1536 + m]) + bioux[m] + biouh[m]);
        float uv = tanhf(bf2f(IOU_r[(size_t)r * 1536 + 1024 + m]) + bioux[1024 + m] + biouh[1024 + m]);
        float fx = bf2f(FX[(size_t)r * 512 + m]) + bfx[m];
        float c = iv * uv;
#pragma unroll
        for (int k = 0; k < 3; ++k) {
            size_t idx = ((size_t)r * 3 + k) * 512 + m;
            float f = sigm(bf2f(FH[idx]) + bfh[m] + fx);
            c += f * bf2f(c_l[idx]);
        }
        c_root[(size_t)r * 512 + m] = c;
    }
}

__global__ __launch_bounds__(256) void final_kernel(
    const float* __restrict__ S, const float* __restrict__ bwh,
    const float* __restrict__ wsum, const float* __restrict__ loss,
    float* __restrict__ out) {
    int b = blockIdx.x, tid = threadIdx.x;
    float w = wsum[tid];
    float bw = bwh[tid];
    float va = sigm(S[(size_t)b * 256 + tid] + bw) * w;
    float vb = sigm(S[(size_t)(512 + b) * 256 + tid] + bw) * w;
    int lane = tid & 63, wid = tid >> 6;
    for (int off = 32; off; off >>= 1) {
        va += __shfl_down(va, off);
        vb += __shfl_down(vb, off);
    }
    __shared__ float ra[4], rb[4];
    if (lane == 0) { ra[wid] = va; rb[wid] = vb; }
    __syncthreads();
    if (tid == 0) {
        float a  = ra[0] + ra[1] + ra[2] + ra[3] + wsum[256];
        float bb = rb[0] + rb[1] + rb[2] + rb[3] + wsum[256];
        out[b] = loss[b] + fmaxf(0.f, 1.f - a + bb);
    }
}

// ---------------- launch ----------------

extern "C" void kernel_launch(void* const* d_in, const int* in_sizes, int n_in,
                              void* d_out, int out_size, void* d_ws, size_t ws_size,
                              hipStream_t stream) {
    const int* q_v   = (const int*)d_in[0];
    const int* q_a0  = (const int*)d_in[1];
    const int* n_a0  = (const int*)d_in[2];
    const int* q_a1  = (const int*)d_in[3];
    const int* n_a1  = (const int*)d_in[4];
    const int* q_a2  = (const int*)d_in[5];
    const int* n_a2  = (const int*)d_in[6];
    const int* query = (const int*)d_in[7];
    const int* pos   = (const int*)d_in[8];
    const int* neg   = (const int*)d_in[9];
    const float* emb   = (const float*)d_in[10];
    const float* Wioux = (const float*)d_in[11];
    const float* bioux = (const float*)d_in[12];
    const float* Wiouh = (const float*)d_in[13];
    const float* biouh = (const float*)d_in[14];
    const float* Wfx   = (const float*)d_in[15];
    const float* bfx   = (const float*)d_in[16];
    const float* Wfh   = (const float*)d_in[17];
    const float* bfh   = (const float*)d_in[18];
    const float* Wwh   = (const float*)d_in[19];
    const float* bwh   = (const float*)d_in[20];
    const float* Wwp   = (const float*)d_in[21];
    const float* bwp   = (const float*)d_in[22];
    float* out = (float*)d_out;

    char* w = (char*)d_ws;
    size_t off = 0;
    auto alloc = [&](size_t bytes) -> void* {
        void* p = (void*)(w + off);
        off = (off + bytes + 255) & ~(size_t)255;
        return p;
    };
    // ---- persistent region ----
    ushort* Wcat_t = (ushort*)alloc((size_t)1536 * 1024 * 2);
    ushort* Wfh_t  = (ushort*)alloc((size_t)512 * 512 * 2);
    ushort* Wfx_t  = (ushort*)alloc((size_t)512 * 512 * 2);
    ushort* Wwh_t  = (ushort*)alloc((size_t)256 * 512 * 2);
    float*  wsum   = (float*) alloc(257 * 4);
    float*  lossv  = (float*) alloc(512 * 4);
    ushort* Xleaf  = (ushort*)alloc((size_t)4608 * 512 * 2);
    ushort* XR     = (ushort*)alloc((size_t)1536 * 1024 * 2);
    // ---- aliased region: phase1 (emb8, pools) then phase2 (GEMM temporaries) ----
    size_t xbase = off;
    unsigned char* emb8 = (unsigned char*)alloc((size_t)50000 * 512);
    float* pools        = (float*)        alloc((size_t)7 * 512 * 512 * 4);
    off = xbase;   // rewind: safe by ordering (emb8 dead after gather; pools dead after dots)
    ushort* IOU_l  = (ushort*)alloc((size_t)4608 * 1536 * 2);
    ushort* c_l    = (ushort*)alloc((size_t)4608 * 512 * 2);
    ushort* h_l    = (ushort*)alloc((size_t)4608 * 512 * 2);
    ushort* FH     = (ushort*)alloc((size_t)4608 * 512 * 2);
    ushort* FX     = (ushort*)alloc((size_t)1536 * 512 * 2);
    ushort* IOU_r  = (ushort*)alloc((size_t)1536 * 1536 * 2);
    float*  c_root = (float*) alloc((size_t)1536 * 512 * 4);
    float*  S      = (float*) alloc((size_t)1024 * 256 * 4);

    prep_all_kernel<<<14677, 256, 0, stream>>>(emb, emb8, Wioux, Wiouh, Wfh, Wfx, Wwh,
                                               Wwp, bwp, Wcat_t, Wfh_t, Wfx_t, Wwh_t, wsum);
    mega_gather_kernel<<<9728, 256, 0, stream>>>(q_v, q_a0, n_a0, q_a1, n_a1, q_a2, n_a2,
                                                 query, pos, neg, emb8, pools, Xleaf, XR);
    g1_dots_kernel<<<944, 256, 0, stream>>>(Xleaf, Wcat_t, IOU_l, pools, lossv);
    leaf_act_kernel<<<1536, 256, 0, stream>>>(IOU_l, bioux, biouh, c_l, h_l, XR);
    gemm3_kernel<<<336, 256, 0, stream>>>(h_l, XR, Wfh_t, Wfx_t, Wcat_t, FH, FX, IOU_r);
    root_act_kernel<<<1536, 256, 0, stream>>>(IOU_r, FH, FX, c_l, bioux, biouh, bfx, bfh, c_root);
    gemm_sim_kernel<<<16, 256, 0, stream>>>(c_root, Wwh_t, S);
    final_kernel<<<512, 256, 0, stream>>>(S, bwh, wsum, lossv, out);
}